// Round 5
// baseline (202.704 us; speedup 1.0000x reference)
//
#include <hip/hip_runtime.h>
#include <hip/hip_bf16.h>

#define B_  8
#define Q_  32
#define LE_ 128
#define D_  512
#define P_  32
#define A_  128

typedef __attribute__((ext_vector_type(8))) short short8_t;   // 8 bf16 (4 VGPRs)
typedef __attribute__((ext_vector_type(4))) float floatx4_t;  // 4 fp32 acc

// fp32 -> bf16 round-to-nearest-even, raw bits
__device__ __forceinline__ short f2bf(float x) {
    unsigned u = __float_as_uint(x);
    unsigned r = (u + 0x7fffu + ((u >> 16) & 1u)) >> 16;
    return (short)r;
}

// ---------------- K1: EW[b,p,a] = exp(2*(s_j[b,p,:]·Ws_w[a,:] + Ws_b[a])) -------
__global__ __launch_bounds__(128) void ws_kernel(
    const float* __restrict__ s_j, const float* __restrict__ Ws_w,
    const float* __restrict__ Ws_b, float* __restrict__ ws) {
    __shared__ float s_row[D_];
    int bp = blockIdx.x;
    const float* src = s_j + (size_t)bp * D_;
    for (int i = threadIdx.x; i < D_; i += 128) s_row[i] = src[i];
    __syncthreads();
    int a = threadIdx.x;
    const float4* w4 = (const float4*)(Ws_w + (size_t)a * D_);
    const float4* s4 = (const float4*)s_row;
    float acc = 0.0f;
#pragma unroll 8
    for (int i = 0; i < D_ / 4; ++i) {
        float4 w = w4[i];
        float4 s = s4[i];
        acc += w.x * s.x + w.y * s.y + w.z * s.z + w.w * s.w;
    }
    ws[bp * A_ + a] = __expf(2.0f * (acc + Ws_b[a]));
}

// ---------------- K2: EU = exp(2*uh), uh via bf16 MFMA ---------------------------
// uh[m][n] = sum_k X[m][k]*W[n][k];  M=32768, N=128, K=512 (NT, both K-contiguous)
// TM=32: grid 1024 = 4 blocks/CU for latency hiding. Block 32M x 128N, BK=64.
#define TM_ 32
#define TBK_ 64
#define LDSP_ 72   // padded LDS row (bf16 elems) = 144 B

__global__ __launch_bounds__(256, 4) void uh_mfma_kernel(
    const float* __restrict__ X, const float* __restrict__ W,
    float* __restrict__ uh) {
    __shared__ short As[TM_ * LDSP_];    // [m][k] bf16  (4.6 KB)
    __shared__ short Bs[A_ * LDSP_];     // [n][k] bf16  (18.4 KB)
    int mblk = blockIdx.x * TM_;
    int tid = threadIdx.x;
    int wave = tid >> 6, lane = tid & 63;
    int qd = lane >> 4, lr = lane & 15;
    int nq = wave;                       // wave n-quarter: cols nq*32..+31

    floatx4_t acc[2][2];
#pragma unroll
    for (int i = 0; i < 2; ++i)
#pragma unroll
        for (int j = 0; j < 2; ++j) acc[i][j] = (floatx4_t){0.f, 0.f, 0.f, 0.f};

    int ra = tid >> 3, ea = tid & 7;     // A staging: row 0..31, col-eighth
    int rb = tid >> 1, hb = tid & 1;     // B staging: row 0..127, 32-col half

    for (int kt = 0; kt < D_ / TBK_; ++kt) {
        int k0 = kt * TBK_;
        __syncthreads();
        {   // stage A: 32 rows x 64 k fp32 -> bf16 (8 floats/thread)
            const float4* src = (const float4*)(X + (size_t)(mblk + ra) * D_ + k0 + ea * 8);
            float4 v0 = src[0];
            float4 v1 = src[1];
            short8_t s;
            s[0] = f2bf(v0.x); s[1] = f2bf(v0.y); s[2] = f2bf(v0.z); s[3] = f2bf(v0.w);
            s[4] = f2bf(v1.x); s[5] = f2bf(v1.y); s[6] = f2bf(v1.z); s[7] = f2bf(v1.w);
            *(short8_t*)(As + ra * LDSP_ + ea * 8) = s;
        }
        {   // stage B: 128 rows x 64 k fp32 -> bf16 (32 floats/thread)
            const float4* src = (const float4*)(W + (size_t)rb * D_ + k0 + hb * 32);
            short* dst = Bs + rb * LDSP_ + hb * 32;
#pragma unroll
            for (int j = 0; j < 4; ++j) {
                float4 v0 = src[j * 2 + 0];
                float4 v1 = src[j * 2 + 1];
                short8_t s;
                s[0] = f2bf(v0.x); s[1] = f2bf(v0.y); s[2] = f2bf(v0.z); s[3] = f2bf(v0.w);
                s[4] = f2bf(v1.x); s[5] = f2bf(v1.y); s[6] = f2bf(v1.z); s[7] = f2bf(v1.w);
                *(short8_t*)(dst + j * 8) = s;
            }
        }
        __syncthreads();
#pragma unroll
        for (int ks = 0; ks < 2; ++ks) {
            short8_t af[2], bfr[2];
#pragma unroll
            for (int i = 0; i < 2; ++i)
                af[i] = *(const short8_t*)(As + (i * 16 + lr) * LDSP_ + ks * 32 + qd * 8);
#pragma unroll
            for (int j = 0; j < 2; ++j)
                bfr[j] = *(const short8_t*)(Bs + (nq * 32 + j * 16 + lr) * LDSP_ + ks * 32 + qd * 8);
#pragma unroll
            for (int i = 0; i < 2; ++i)
#pragma unroll
                for (int j = 0; j < 2; ++j)
                    acc[i][j] = __builtin_amdgcn_mfma_f32_16x16x32_bf16(af[i], bfr[j], acc[i][j], 0, 0, 0);
        }
    }
    // C/D: col = lane&15 (n), row = qd*4+reg (m); store EU = exp(2*uh)
#pragma unroll
    for (int i = 0; i < 2; ++i) {
#pragma unroll
        for (int j = 0; j < 2; ++j) {
            int mg = mblk + i * 16 + qd * 4;
            int ng = nq * 32 + j * 16 + lr;
            float* dst = uh + (size_t)mg * A_ + ng;
#pragma unroll
            for (int r = 0; r < 4; ++r)
                dst[(size_t)r * A_] = __expf(2.0f * acc[i][j][r]);
        }
    }
}

// -------- K3: e[b,q,p,t] = sumv - sum_a 2*v[a]/(1 + EU[bq,t,a]*EW[b,p,a]) -------
__global__ __launch_bounds__(256) void score_kernel(
    const float* __restrict__ EU, const float* __restrict__ EW,
    const float* __restrict__ v_w, const int* __restrict__ exp_mask,
    float* __restrict__ e) {
    __shared__ float eu_t[32][132];  // [t][a], padded
    __shared__ float ew_t[32][128];  // [p][a]
    __shared__ float n2v[128];       // -2*v[a]
    int blk = blockIdx.x;
    int bq = blk >> 2, tc = blk & 3;
    int b = bq >> 5;  // Q=32
    int t0 = tc * 32;
    int tid = threadIdx.x;

#pragma unroll
    for (int i = 0; i < 4; ++i) {
        int f = tid + i * 256;          // 0..1023
        int t = f >> 5, a4 = f & 31;
        float4 v = *(const float4*)(EU + (size_t)(bq * LE_ + t0 + t) * A_ + a4 * 4);
        *(float4*)&eu_t[t][a4 * 4] = v;
    }
#pragma unroll
    for (int i = 0; i < 4; ++i) {
        int f = tid + i * 256;
        int p = f >> 5, a4 = f & 31;
        *(float4*)&ew_t[p][a4 * 4] =
            *(const float4*)(EW + (size_t)(b * P_ + p) * A_ + a4 * 4);
    }
    if (tid < 32) {
        float4 v = *(const float4*)(v_w + tid * 4);
        v.x *= -2.0f; v.y *= -2.0f; v.z *= -2.0f; v.w *= -2.0f;
        *(float4*)&n2v[tid * 4] = v;
    }
    __syncthreads();

    float sumv = 0.0f;
#pragma unroll
    for (int i = 0; i < 32; ++i) {
        float4 nv = *(const float4*)&n2v[i * 4];
        sumv += nv.x + nv.y + nv.z + nv.w;
    }
    sumv *= -0.5f;

    int t = tid & 31, pb = tid >> 5;  // pb 0..7
    int mask = exp_mask[bq * LE_ + t0 + t];
    float acc[4] = {0.f, 0.f, 0.f, 0.f};
    for (int a4 = 0; a4 < 32; ++a4) {
        float4 u = *(const float4*)&eu_t[t][a4 * 4];
        float4 vv = *(const float4*)&n2v[a4 * 4];
#pragma unroll
        for (int i = 0; i < 4; ++i) {
            float4 w = *(const float4*)&ew_t[pb + i * 8][a4 * 4];
            acc[i] = fmaf(vv.x, __builtin_amdgcn_rcpf(fmaf(u.x, w.x, 1.0f)), acc[i]);
            acc[i] = fmaf(vv.y, __builtin_amdgcn_rcpf(fmaf(u.y, w.y, 1.0f)), acc[i]);
            acc[i] = fmaf(vv.z, __builtin_amdgcn_rcpf(fmaf(u.z, w.z, 1.0f)), acc[i]);
            acc[i] = fmaf(vv.w, __builtin_amdgcn_rcpf(fmaf(u.w, w.w, 1.0f)), acc[i]);
        }
    }
#pragma unroll
    for (int i = 0; i < 4; ++i) {
        int p = pb + i * 8;
        e[(size_t)(bq * P_ + p) * LE_ + t0 + t] = mask ? (sumv + acc[i]) : -1e9f;
    }
}

// -------- K4: per (b,p): rinv = 1 / sum_{q,t} exp(e)  (max-free softmax) --------
__global__ __launch_bounds__(256) void softmax_stats_kernel(
    const float* __restrict__ e, float* __restrict__ rinv) {
    __shared__ float red[4];
    int bp = blockIdx.x;
    int b = bp >> 5, p = bp & 31;  // P=32
    int tid = threadIdx.x;
    float s = 0.0f;
#pragma unroll
    for (int i = 0; i < 16; ++i) {
        int idx = tid + i * 256;  // 0..4095
        int q = idx >> 7, t = idx & 127;
        s += __expf(e[(size_t)((b * Q_ + q) * P_ + p) * LE_ + t]);
    }
    for (int off = 32; off; off >>= 1) s += __shfl_down(s, off);
    int wid = tid >> 6;
    if ((tid & 63) == 0) red[wid] = s;
    __syncthreads();
    if (tid == 0)
        rinv[bp] = 1.0f / (red[0] + red[1] + red[2] + red[3]);
}

// -------- K5: out[b,q,p,d] = req_mask[b,p] * sum_t exp(e)*rinv*T[b,q,t,d] ------
// grid: bq*2 + phalf ; 256 thr, each thread a d-PAIR (float2, pk-fma), 16 p accs
#define WSTRIDE 20
__global__ __launch_bounds__(256) void out_kernel(
    const float* __restrict__ e, const float* __restrict__ rinv,
    const float* __restrict__ exp_tokens, const int* __restrict__ req_mask,
    float* __restrict__ out) {
    __shared__ float w_s[LE_ * WSTRIDE];  // [t][p16 pad20] = 10 KB
    int bq = blockIdx.x >> 1, ph = blockIdx.x & 1;
    int b = bq >> 5;  // Q=32
    int p0 = ph * 16;
    int tid = threadIdx.x;

#pragma unroll
    for (int i = 0; i < 8; ++i) {
        int idx = tid + i * 256;  // 0..2047
        int t = idx & 127, p = idx >> 7;   // p 0..15
        int bp = b * P_ + p0 + p;
        float rm = req_mask[bp] ? rinv[bp] : 0.0f;
        float ev = e[(size_t)(bq * P_ + p0 + p) * LE_ + t];
        w_s[t * WSTRIDE + p] = __expf(ev) * rm;
    }
    __syncthreads();

    int d0 = tid * 2;
    const float* T = exp_tokens + (size_t)bq * LE_ * D_;
    float2 acc2[16];
#pragma unroll
    for (int p = 0; p < 16; ++p) acc2[p] = make_float2(0.f, 0.f);

#pragma unroll 4
    for (int t = 0; t < LE_; ++t) {
        float2 tv = *(const float2*)&T[(size_t)t * D_ + d0];
        const float4* wp = (const float4*)&w_s[t * WSTRIDE];
#pragma unroll
        for (int j = 0; j < 4; ++j) {
            float4 w = wp[j];
            acc2[j * 4 + 0].x = fmaf(w.x, tv.x, acc2[j * 4 + 0].x);
            acc2[j * 4 + 0].y = fmaf(w.x, tv.y, acc2[j * 4 + 0].y);
            acc2[j * 4 + 1].x = fmaf(w.y, tv.x, acc2[j * 4 + 1].x);
            acc2[j * 4 + 1].y = fmaf(w.y, tv.y, acc2[j * 4 + 1].y);
            acc2[j * 4 + 2].x = fmaf(w.z, tv.x, acc2[j * 4 + 2].x);
            acc2[j * 4 + 2].y = fmaf(w.z, tv.y, acc2[j * 4 + 2].y);
            acc2[j * 4 + 3].x = fmaf(w.w, tv.x, acc2[j * 4 + 3].x);
            acc2[j * 4 + 3].y = fmaf(w.w, tv.y, acc2[j * 4 + 3].y);
        }
    }
    float* obase = out + (size_t)(bq * P_ + p0) * D_ + d0;
#pragma unroll
    for (int p = 0; p < 16; ++p)
        *(float2*)(obase + (size_t)p * D_) = acc2[p];
}

extern "C" void kernel_launch(void* const* d_in, const int* in_sizes, int n_in,
                              void* d_out, int out_size, void* d_ws, size_t ws_size,
                              hipStream_t stream) {
    const float* exp_tokens = (const float*)d_in[0];
    const int*   exp_mask   = (const int*)d_in[1];
    const float* s_j        = (const float*)d_in[2];
    const int*   req_mask   = (const int*)d_in[3];
    const float* Ws_w       = (const float*)d_in[4];
    const float* Ws_b       = (const float*)d_in[5];
    const float* U_w        = (const float*)d_in[6];
    const float* v_w        = (const float*)d_in[7];
    float* out = (float*)d_out;

    float* ws_buf = (float*)d_ws;                         // B*P*A      = 32768   (EW)
    float* uh     = ws_buf + B_ * P_ * A_;                // B*Q*LE*A   = 4194304 (EU)
    float* e      = uh + (size_t)B_ * Q_ * LE_ * A_;      // B*Q*P*LE   = 1048576
    float* rinv   = e + (size_t)B_ * Q_ * P_ * LE_;       // B*P        = 256

    ws_kernel<<<dim3(B_ * P_), dim3(128), 0, stream>>>(s_j, Ws_w, Ws_b, ws_buf);
    uh_mfma_kernel<<<dim3(B_ * Q_ * LE_ / TM_), dim3(256), 0, stream>>>(exp_tokens, U_w, uh);
    score_kernel<<<dim3(B_ * Q_ * 4), dim3(256), 0, stream>>>(uh, ws_buf, v_w, exp_mask, e);
    softmax_stats_kernel<<<dim3(B_ * P_), dim3(256), 0, stream>>>(e, rinv);
    out_kernel<<<dim3(B_ * Q_ * 2), dim3(256), 0, stream>>>(e, rinv, exp_tokens, req_mask, out);
}

// Round 7
// 183.083 us; speedup vs baseline: 1.1072x; 1.1072x over previous
//
#include <hip/hip_runtime.h>
#include <hip/hip_bf16.h>

#define B_  8
#define Q_  32
#define LE_ 128
#define D_  512
#define P_  32
#define A_  128

typedef __attribute__((ext_vector_type(8))) short short8_t;   // 8 bf16 (4 VGPRs)
typedef __attribute__((ext_vector_type(4))) float floatx4_t;  // 4 fp32 acc
typedef float f32x2 __attribute__((ext_vector_type(2)));

typedef const __attribute__((address_space(1))) unsigned int glb_uint;
typedef __attribute__((address_space(3))) unsigned int lds_uint;
#define GLD16(g, s) __builtin_amdgcn_global_load_lds((glb_uint*)(g), (lds_uint*)(s), 16, 0, 0)

// fp32 -> bf16 round-to-nearest-even, raw bits
__device__ __forceinline__ short f2bf(float x) {
    unsigned u = __float_as_uint(x);
    unsigned r = (u + 0x7fffu + ((u >> 16) & 1u)) >> 16;
    return (short)r;
}

// ---------------- K0: convert X (16.7M) and W (64K) fp32 -> bf16 -----------------
// X = 8192 blocks * 2048 floats; W = 32 blocks * 2048 floats.
__global__ __launch_bounds__(256) void convert_kernel(
    const float* __restrict__ X, const float* __restrict__ W,
    short* __restrict__ Xb, short* __restrict__ Wb) {
    int b = blockIdx.x;
    const float* src;
    short* dst;
    size_t base;
    if (b < 8192) {
        base = ((size_t)b * 256 + threadIdx.x) * 8;
        src = X + base; dst = Xb + base;
    } else {
        base = ((size_t)(b - 8192) * 256 + threadIdx.x) * 8;
        src = W + base; dst = Wb + base;
    }
    float4 v0 = ((const float4*)src)[0];
    float4 v1 = ((const float4*)src)[1];
    short8_t s;
    s[0] = f2bf(v0.x); s[1] = f2bf(v0.y); s[2] = f2bf(v0.z); s[3] = f2bf(v0.w);
    s[4] = f2bf(v1.x); s[5] = f2bf(v1.y); s[6] = f2bf(v1.z); s[7] = f2bf(v1.w);
    *(short8_t*)dst = s;
}

// ---------------- K1: EW[b,p,a] = exp(2*(s_j[b,p,:]·Ws_w[a,:] + Ws_b[a])) -------
__global__ __launch_bounds__(128) void ws_kernel(
    const float* __restrict__ s_j, const float* __restrict__ Ws_w,
    const float* __restrict__ Ws_b, float* __restrict__ ws) {
    __shared__ float s_row[D_];
    int bp = blockIdx.x;
    const float* src = s_j + (size_t)bp * D_;
    for (int i = threadIdx.x; i < D_; i += 128) s_row[i] = src[i];
    __syncthreads();
    int a = threadIdx.x;
    const float4* w4 = (const float4*)(Ws_w + (size_t)a * D_);
    const float4* s4 = (const float4*)s_row;
    float acc = 0.0f;
#pragma unroll 8
    for (int i = 0; i < D_ / 4; ++i) {
        float4 w = w4[i];
        float4 s = s4[i];
        acc += w.x * s.x + w.y * s.y + w.z * s.z + w.w * s.w;
    }
    ws[bp * A_ + a] = __expf(2.0f * (acc + Ws_b[a]));
}

// ---------------- K2: EU = exp(2*uh); bf16 MFMA, global_load_lds staging --------
// uh[m][n] = sum_k Xb[m][k]*Wb[n][k];  M=32768, N=128, K=512
// Block 64M x 128N, BK=64; 4 waves, wave tile 32M x 64N; XOR-swizzled LDS.
__global__ __launch_bounds__(256, 2) void uh_mfma_kernel(
    const short* __restrict__ Xb, const short* __restrict__ Wb,
    float* __restrict__ uh) {
    __shared__ short As[64 * 64];    // 8 KB, [m][8 chunks of 8 bf16], chunk-swizzled
    __shared__ short Bs[128 * 64];   // 16 KB
    int mblk = blockIdx.x * 64;
    int tid = threadIdx.x;
    int wave = tid >> 6, lane = tid & 63;
    int qd = lane >> 4, lr = lane & 15;
    int mh = wave >> 1, nh = wave & 1;
    int axor = lr & 7;               // (row&7) for all fragment rows this lane reads

    // staging source precompute (lane-invariant parts)
    int cA = lane & 7;               // chunk slot within row
    int rowA0 = wave * 16 + (lane >> 3);          // +8 for u=1
    int rowB0 = wave * 32 + (lane >> 3);          // +8*u for u=0..3

    floatx4_t acc[2][4];
#pragma unroll
    for (int i = 0; i < 2; ++i)
#pragma unroll
        for (int j = 0; j < 4; ++j) acc[i][j] = (floatx4_t){0.f, 0.f, 0.f, 0.f};

    for (int kt = 0; kt < 8; ++kt) {
        int k0 = kt * 64;
        if (kt) __syncthreads();
        // stage A: 64 rows x 64 k, 8 issues (2 per wave)
#pragma unroll
        for (int u = 0; u < 2; ++u) {
            int m = rowA0 + u * 8;
            const short* g = Xb + (size_t)(mblk + m) * D_ + k0 + ((cA ^ (m & 7)) * 8);
            GLD16(g, As + (wave * 2 + u) * 512);
        }
        // stage B: 128 rows x 64 k, 16 issues (4 per wave)
#pragma unroll
        for (int u = 0; u < 4; ++u) {
            int n = rowB0 + u * 8;
            const short* g = Wb + (size_t)n * D_ + k0 + ((cA ^ (n & 7)) * 8);
            GLD16(g, Bs + (wave * 4 + u) * 512);
        }
        __syncthreads();
#pragma unroll
        for (int ks = 0; ks < 2; ++ks) {
            int cr = (ks * 4 + qd) ^ axor;
            short8_t af[2], bfr[4];
#pragma unroll
            for (int i = 0; i < 2; ++i)
                af[i] = *(const short8_t*)(As + (mh * 32 + i * 16 + lr) * 64 + cr * 8);
#pragma unroll
            for (int j = 0; j < 4; ++j)
                bfr[j] = *(const short8_t*)(Bs + (nh * 64 + j * 16 + lr) * 64 + cr * 8);
#pragma unroll
            for (int i = 0; i < 2; ++i)
#pragma unroll
                for (int j = 0; j < 4; ++j)
                    acc[i][j] = __builtin_amdgcn_mfma_f32_16x16x32_bf16(af[i], bfr[j], acc[i][j], 0, 0, 0);
        }
    }
    // C/D: col = lane&15 (n), row = qd*4+reg (m); store EU = exp(2*uh)
#pragma unroll
    for (int i = 0; i < 2; ++i) {
#pragma unroll
        for (int j = 0; j < 4; ++j) {
            int mg = mblk + mh * 32 + i * 16 + qd * 4;
            int ng = nh * 64 + j * 16 + lr;
            float* dst = uh + (size_t)mg * A_ + ng;
#pragma unroll
            for (int r = 0; r < 4; ++r)
                dst[(size_t)r * A_] = __expf(2.0f * acc[i][j][r]);
        }
    }
}

// -------- K3: Ee[b,q,p,t] = mask ? exp(-sum_a 2*v[a]/(1+EU*EW)) : 0 ------------
// (softmax shift-invariance: the +sum_a v[a] constant cancels -> omitted)
__global__ __launch_bounds__(256) void score_kernel(
    const float* __restrict__ EU, const float* __restrict__ EW,
    const float* __restrict__ v_w, const int* __restrict__ exp_mask,
    float* __restrict__ Ee) {
    __shared__ float eu_t[32][132];  // [t][a], padded
    __shared__ float ew_t[32][128];  // [p][a]
    __shared__ float n2v[128];       // -2*v[a]
    int blk = blockIdx.x;
    int bq = blk >> 2, tc = blk & 3;
    int b = bq >> 5;  // Q=32
    int t0 = tc * 32;
    int tid = threadIdx.x;

#pragma unroll
    for (int i = 0; i < 4; ++i) {
        int f = tid + i * 256;          // 0..1023
        int t = f >> 5, a4 = f & 31;
        float4 v = *(const float4*)(EU + (size_t)(bq * LE_ + t0 + t) * A_ + a4 * 4);
        *(float4*)&eu_t[t][a4 * 4] = v;
    }
#pragma unroll
    for (int i = 0; i < 4; ++i) {
        int f = tid + i * 256;
        int p = f >> 5, a4 = f & 31;
        *(float4*)&ew_t[p][a4 * 4] =
            *(const float4*)(EW + (size_t)(b * P_ + p) * A_ + a4 * 4);
    }
    if (tid < 32) {
        float4 v = *(const float4*)(v_w + tid * 4);
        v.x *= -2.0f; v.y *= -2.0f; v.z *= -2.0f; v.w *= -2.0f;
        *(float4*)&n2v[tid * 4] = v;
    }
    __syncthreads();

    int t = tid & 31, pb = tid >> 5;  // pb 0..7
    int mask = exp_mask[bq * LE_ + t0 + t];
    float acc[4] = {0.f, 0.f, 0.f, 0.f};
    for (int a4 = 0; a4 < 32; ++a4) {
        float4 u = *(const float4*)&eu_t[t][a4 * 4];
        float4 vv = *(const float4*)&n2v[a4 * 4];
#pragma unroll
        for (int i = 0; i < 4; ++i) {
            float4 w = *(const float4*)&ew_t[pb + i * 8][a4 * 4];
            acc[i] = fmaf(vv.x, __builtin_amdgcn_rcpf(fmaf(u.x, w.x, 1.0f)), acc[i]);
            acc[i] = fmaf(vv.y, __builtin_amdgcn_rcpf(fmaf(u.y, w.y, 1.0f)), acc[i]);
            acc[i] = fmaf(vv.z, __builtin_amdgcn_rcpf(fmaf(u.z, w.z, 1.0f)), acc[i]);
            acc[i] = fmaf(vv.w, __builtin_amdgcn_rcpf(fmaf(u.w, w.w, 1.0f)), acc[i]);
        }
    }
#pragma unroll
    for (int i = 0; i < 4; ++i) {
        int p = pb + i * 8;
        Ee[(size_t)(bq * P_ + p) * LE_ + t0 + t] = mask ? __expf(acc[i]) : 0.0f;
    }
}

// -------- K4: per (b,p): rinv = 1 / sum_{q,t} Ee ------------------------------
__global__ __launch_bounds__(256) void softmax_stats_kernel(
    const float* __restrict__ Ee, float* __restrict__ rinv) {
    __shared__ float red[4];
    int bp = blockIdx.x;
    int b = bp >> 5, p = bp & 31;  // P=32
    int tid = threadIdx.x;
    float s = 0.0f;
#pragma unroll
    for (int i = 0; i < 16; ++i) {
        int idx = tid + i * 256;  // 0..4095
        int q = idx >> 7, t = idx & 127;
        s += Ee[(size_t)((b * Q_ + q) * P_ + p) * LE_ + t];
    }
    for (int off = 32; off; off >>= 1) s += __shfl_down(s, off);
    int wid = tid >> 6;
    if ((tid & 63) == 0) red[wid] = s;
    __syncthreads();
    if (tid == 0)
        rinv[bp] = 1.0f / (red[0] + red[1] + red[2] + red[3]);
}

// -------- K5: out[b,q,p,d] = req_mask * sum_t Ee*rinv*Tb[t,d] (bf16 T, pk-fma) -
#define WSTRIDE 20
__global__ __launch_bounds__(256) void out_kernel(
    const float* __restrict__ Ee, const float* __restrict__ rinv,
    const short* __restrict__ Xb, const int* __restrict__ req_mask,
    float* __restrict__ out) {
    __shared__ float w_s[LE_ * WSTRIDE];  // [t][p16 pad20] = 10 KB
    int bq = blockIdx.x >> 1, ph = blockIdx.x & 1;
    int b = bq >> 5;  // Q=32
    int p0 = ph * 16;
    int tid = threadIdx.x;

#pragma unroll
    for (int i = 0; i < 8; ++i) {
        int idx = tid + i * 256;  // 0..2047
        int t = idx & 127, p = idx >> 7;   // p 0..15
        int bp = b * P_ + p0 + p;
        float rm = req_mask[bp] ? rinv[bp] : 0.0f;
        w_s[t * WSTRIDE + p] = Ee[(size_t)(bq * P_ + p0 + p) * LE_ + t] * rm;
    }
    __syncthreads();

    const unsigned* Tb = (const unsigned*)(Xb + (size_t)bq * LE_ * D_);
    f32x2 acc2[16];
#pragma unroll
    for (int p = 0; p < 16; ++p) acc2[p] = (f32x2){0.f, 0.f};

#pragma unroll 4
    for (int t = 0; t < LE_; ++t) {
        unsigned uv = Tb[t * (D_ / 2) + tid];   // 2 bf16 (d0, d0+1)
        f32x2 tv = (f32x2){__uint_as_float(uv << 16),
                           __uint_as_float(uv & 0xffff0000u)};
        const float4* wp = (const float4*)&w_s[t * WSTRIDE];
#pragma unroll
        for (int j = 0; j < 4; ++j) {
            float4 w = wp[j];
            acc2[j * 4 + 0] = (f32x2){w.x, w.x} * tv + acc2[j * 4 + 0];
            acc2[j * 4 + 1] = (f32x2){w.y, w.y} * tv + acc2[j * 4 + 1];
            acc2[j * 4 + 2] = (f32x2){w.z, w.z} * tv + acc2[j * 4 + 2];
            acc2[j * 4 + 3] = (f32x2){w.w, w.w} * tv + acc2[j * 4 + 3];
        }
    }
    float* obase = out + (size_t)(bq * P_ + p0) * D_ + tid * 2;
#pragma unroll
    for (int p = 0; p < 16; ++p)
        *(float2*)(obase + (size_t)p * D_) = make_float2(acc2[p].x, acc2[p].y);
}

extern "C" void kernel_launch(void* const* d_in, const int* in_sizes, int n_in,
                              void* d_out, int out_size, void* d_ws, size_t ws_size,
                              hipStream_t stream) {
    const float* exp_tokens = (const float*)d_in[0];
    const int*   exp_mask   = (const int*)d_in[1];
    const float* s_j        = (const float*)d_in[2];
    const int*   req_mask   = (const int*)d_in[3];
    const float* Ws_w       = (const float*)d_in[4];
    const float* Ws_b       = (const float*)d_in[5];
    const float* U_w        = (const float*)d_in[6];
    const float* v_w        = (const float*)d_in[7];
    float* out = (float*)d_out;

    float* ws_buf = (float*)d_ws;                         // EW:   B*P*A    = 32768
    float* uh     = ws_buf + B_ * P_ * A_;                // EU:   B*Q*LE*A = 4194304
    float* Ee     = uh + (size_t)B_ * Q_ * LE_ * A_;      // Ee:   B*Q*P*LE = 1048576
    float* rinv   = Ee + (size_t)B_ * Q_ * P_ * LE_;      // B*P = 256
    short* Xb     = (short*)(rinv + 256);                 // 16.7M bf16
    short* Wb     = Xb + (size_t)B_ * Q_ * LE_ * D_;      // 64K bf16

    convert_kernel<<<dim3(8192 + 32), dim3(256), 0, stream>>>(exp_tokens, U_w, Xb, Wb);
    ws_kernel<<<dim3(B_ * P_), dim3(128), 0, stream>>>(s_j, Ws_w, Ws_b, ws_buf);
    uh_mfma_kernel<<<dim3(B_ * Q_ * LE_ / 64), dim3(256), 0, stream>>>(Xb, Wb, uh);
    score_kernel<<<dim3(B_ * Q_ * 4), dim3(256), 0, stream>>>(uh, ws_buf, v_w, exp_mask, Ee);
    softmax_stats_kernel<<<dim3(B_ * P_), dim3(256), 0, stream>>>(Ee, rinv);
    out_kernel<<<dim3(B_ * Q_ * 2), dim3(256), 0, stream>>>(Ee, rinv, Xb, req_mask, out);
}